// Round 4
// baseline (267.806 us; speedup 1.0000x reference)
//
#include <hip/hip_runtime.h>
#include <hip/hip_bf16.h>
#include <string.h>

// MHA B=2,S=2048,D=1024,H=16,Hd=64. Inputs fp32, output fp32.
// R22: attn de-staging. Every wave reads IDENTICAL K/V fragments (addresses
// depend only on lane, not wave) and K+V per head = 512KB is L2-resident,
// so LDS staging bought nothing (m169/m177). K/V fragments now read
// directly from global via 4 incremented base pointers; LDS and ALL main-
// loop barriers removed -- waves fully independent. Math unchanged
// (32x32 MFMA, swapped QK^T, in-register P via cvt_pk+permlane).
// GEMMs/preps unchanged.

#define DM 1024
#define S_LEN 2048
#define NH 16
#define HD 64

using u16 = unsigned short;
using u32 = unsigned int;

typedef short bf16x8 __attribute__((ext_vector_type(8)));
typedef float f32x4  __attribute__((ext_vector_type(4)));
typedef float f32x16 __attribute__((ext_vector_type(16)));
typedef unsigned int u32x2 __attribute__((ext_vector_type(2)));

__device__ __forceinline__ u16 f2bf(float f) {
    u32 i = __float_as_uint(f);
    u32 r = i + 0x7fffu + ((i >> 16) & 1u);  // RNE
    return (u16)(r >> 16);
}
__device__ __forceinline__ u32 pk_bf16(float a, float b) {  // low16=a, high16=b (RNE)
    __hip_bfloat162 h = __float22bfloat162_rn(float2{a, b});
    u32 r; memcpy(&r, &h, 4);
    return r;
}

// ---- prep: x fp32 -> bf16 ----
__global__ __launch_bounds__(256) void prep_x(const float* __restrict__ X, u16* __restrict__ out) {
    int i = (blockIdx.x * 256 + threadIdx.x) * 4;
    float4 v = *(const float4*)(X + i);
    *(uint2*)(out + i) = make_uint2(pk_bf16(v.x, v.y), pk_bf16(v.z, v.w));
}

// ---- prep: W fp32 [K][N] -> W^T bf16 [N][K] ----
__global__ __launch_bounds__(256) void prep_wt3(
    const float* __restrict__ W0, const float* __restrict__ W1, const float* __restrict__ W2,
    u16* __restrict__ T0, u16* __restrict__ T1, u16* __restrict__ T2)
{
    __shared__ u16 tile[64][72];
    const float* W = (blockIdx.z == 0) ? W0 : (blockIdx.z == 1) ? W1 : W2;
    u16* WT        = (blockIdx.z == 0) ? T0 : (blockIdx.z == 1) ? T1 : T2;
    const int t = threadIdx.x;
    const int n0 = blockIdx.x * 64, k0 = blockIdx.y * 64;
    #pragma unroll
    for (int it = 0; it < 4; it++) {
        int k = it * 16 + (t >> 4);
        int n = (t & 15) * 4;
        float4 v = *(const float4*)(W + (size_t)(k0 + k) * DM + n0 + n);
        tile[n + 0][k] = f2bf(v.x);
        tile[n + 1][k] = f2bf(v.y);
        tile[n + 2][k] = f2bf(v.z);
        tile[n + 3][k] = f2bf(v.w);
    }
    __syncthreads();
    int n = t >> 2, kg = (t & 3) * 16;
    uint4 a = *(const uint4*)&tile[n][kg];
    uint4 b = *(const uint4*)&tile[n][kg + 8];
    *(uint4*)(WT + (size_t)(n0 + n) * DM + k0 + kg)     = a;
    *(uint4*)(WT + (size_t)(n0 + n) * DM + k0 + kg + 8) = b;
}

__global__ __launch_bounds__(256) void prep_wt1(const float* __restrict__ W, u16* __restrict__ WT) {
    __shared__ u16 tile[64][72];
    const int t = threadIdx.x;
    const int n0 = blockIdx.x * 64, k0 = blockIdx.y * 64;
    #pragma unroll
    for (int it = 0; it < 4; it++) {
        int k = it * 16 + (t >> 4);
        int n = (t & 15) * 4;
        float4 v = *(const float4*)(W + (size_t)(k0 + k) * DM + n0 + n);
        tile[n + 0][k] = f2bf(v.x);
        tile[n + 1][k] = f2bf(v.y);
        tile[n + 2][k] = f2bf(v.z);
        tile[n + 3][k] = f2bf(v.w);
    }
    __syncthreads();
    int n = t >> 2, kg = (t & 3) * 16;
    uint4 a = *(const uint4*)&tile[n][kg];
    uint4 b = *(const uint4*)&tile[n][kg + 8];
    *(uint4*)(WT + (size_t)(n0 + n) * DM + k0 + kg)     = a;
    *(uint4*)(WT + (size_t)(n0 + n) * DM + k0 + kg + 8) = b;
}

// ---- fused QKV projection, LDS-staged. Block: 64 feat x 128 tok, BK=64. ----
__global__ __launch_bounds__(256) void gemm_qkv(
    const u16* __restrict__ WQT, const u16* __restrict__ WKT, const u16* __restrict__ WVT,
    const u16* __restrict__ X,
    const float* __restrict__ bq, const float* __restrict__ bk, const float* __restrict__ bv,
    u16* __restrict__ outQ, u16* __restrict__ outK, u16* __restrict__ outVT)
{
    __shared__ u16 Xs[128][72];
    __shared__ u16 Ws[3][64][72];

    const int t = threadIdx.x;
    const int w = t >> 6, lane = t & 63, quad = lane >> 4, l16 = lane & 15;
    const int Mb0 = blockIdx.x * 64;
    const int Nb0 = blockIdx.y * 128;
    const int Mb = Mb0 + (w & 1) * 32;
    const int Nb = Nb0 + (w >> 1) * 64;
    const int mloc = (w & 1) * 32, nloc = (w >> 1) * 64;

    f32x4 acc[3][2][4];
    #pragma unroll
    for (int q = 0; q < 3; q++)
        #pragma unroll
        for (int i = 0; i < 2; i++)
            #pragma unroll
            for (int j = 0; j < 4; j++) acc[q][i][j] = (f32x4){0.f, 0.f, 0.f, 0.f};

    const int sr = t >> 3, sc8 = (t & 7) * 8;

    for (int k0 = 0; k0 < DM; k0 += 64) {
        __syncthreads();
        #pragma unroll
        for (int i = 0; i < 4; i++) {
            int r = i * 32 + sr;
            *(uint4*)&Xs[r][sc8] =
                *(const uint4*)(X + (size_t)(Nb0 + r) * DM + k0 + sc8);
        }
        #pragma unroll
        for (int i = 0; i < 2; i++) {
            int r = i * 32 + sr;
            *(uint4*)&Ws[0][r][sc8] = *(const uint4*)(WQT + (size_t)(Mb0 + r) * DM + k0 + sc8);
            *(uint4*)&Ws[1][r][sc8] = *(const uint4*)(WKT + (size_t)(Mb0 + r) * DM + k0 + sc8);
            *(uint4*)&Ws[2][r][sc8] = *(const uint4*)(WVT + (size_t)(Mb0 + r) * DM + k0 + sc8);
        }
        __syncthreads();

        #pragma unroll
        for (int ks = 0; ks < 2; ks++) {
            const int kk = ks * 32 + quad * 8;
            bf16x8 bf[4];
            #pragma unroll
            for (int nt = 0; nt < 4; nt++)
                bf[nt] = *(const bf16x8*)&Xs[nloc + nt * 16 + l16][kk];
            bf16x8 aq0 = *(const bf16x8*)&Ws[0][mloc + l16][kk];
            bf16x8 aq1 = *(const bf16x8*)&Ws[0][mloc + 16 + l16][kk];
            bf16x8 ak0 = *(const bf16x8*)&Ws[1][mloc + l16][kk];
            bf16x8 ak1 = *(const bf16x8*)&Ws[1][mloc + 16 + l16][kk];
            bf16x8 av0 = *(const bf16x8*)&Ws[2][mloc + l16][kk];
            bf16x8 av1 = *(const bf16x8*)&Ws[2][mloc + 16 + l16][kk];
            #pragma unroll
            for (int nt = 0; nt < 4; nt++) {
                acc[0][0][nt] = __builtin_amdgcn_mfma_f32_16x16x32_bf16(aq0, bf[nt], acc[0][0][nt], 0, 0, 0);
                acc[0][1][nt] = __builtin_amdgcn_mfma_f32_16x16x32_bf16(aq1, bf[nt], acc[0][1][nt], 0, 0, 0);
                acc[1][0][nt] = __builtin_amdgcn_mfma_f32_16x16x32_bf16(ak0, bf[nt], acc[1][0][nt], 0, 0, 0);
                acc[1][1][nt] = __builtin_amdgcn_mfma_f32_16x16x32_bf16(ak1, bf[nt], acc[1][1][nt], 0, 0, 0);
                acc[2][0][nt] = __builtin_amdgcn_mfma_f32_16x16x32_bf16(av0, bf[nt], acc[2][0][nt], 0, 0, 0);
                acc[2][1][nt] = __builtin_amdgcn_mfma_f32_16x16x32_bf16(av1, bf[nt], acc[2][1][nt], 0, 0, 0);
            }
        }
    }

    const float QS = 0.18033688f;  // 0.125 * log2(e): attn uses raw v_exp (2^x)
    #pragma unroll
    for (int mt = 0; mt < 2; mt++) {
        int nf0 = Mb + mt * 16 + quad * 4;
        int h = nf0 >> 6, hd = nf0 & 63;
        float4 bvq = *(const float4*)(bq + nf0);
        float4 bvk = *(const float4*)(bk + nf0);
        #pragma unroll
        for (int nt = 0; nt < 4; nt++) {
            int m = Nb + nt * 16 + l16;
            int b = m >> 11, s = m & 2047;
            size_t idx = (size_t)(b * NH + h) * 131072 + (size_t)s * 64 + hd;
            *(uint2*)(outQ + idx) = make_uint2(
                pk_bf16((acc[0][mt][nt][0] + bvq.x) * QS, (acc[0][mt][nt][1] + bvq.y) * QS),
                pk_bf16((acc[0][mt][nt][2] + bvq.z) * QS, (acc[0][mt][nt][3] + bvq.w) * QS));
            *(uint2*)(outK + idx) = make_uint2(
                pk_bf16(acc[1][mt][nt][0] + bvk.x, acc[1][mt][nt][1] + bvk.y),
                pk_bf16(acc[1][mt][nt][2] + bvk.z, acc[1][mt][nt][3] + bvk.w));
        }
    }
    #pragma unroll
    for (int mt = 0; mt < 2; mt++) {
        #pragma unroll
        for (int r = 0; r < 4; r++) {
            int nf = Mb + mt * 16 + quad * 4 + r;
            int h = nf >> 6, hd = nf & 63;
            float bb = bv[nf];
            #pragma unroll
            for (int nt = 0; nt < 4; nt++) {
                int m = Nb + nt * 16 + l16;
                int b = m >> 11, s = m & 2047;
                outVT[(size_t)(b * NH + h) * 131072 + (size_t)hd * S_LEN + s]
                    = f2bf(acc[2][mt][nt][r] + bb);
            }
        }
    }
}

// ---- out GEMM, LDS-staged. Block: 64 feat x 128 tok, BK=64. ----
__global__ __launch_bounds__(256) void gemm_out(
    const u16* __restrict__ A, const u16* __restrict__ B,
    const float* __restrict__ bias, float* __restrict__ of32)
{
    __shared__ u16 As[64][72];
    __shared__ u16 Bs[128][72];

    const int t = threadIdx.x;
    const int w = t >> 6, lane = t & 63, quad = lane >> 4, l16 = lane & 15;
    const int Mb0 = blockIdx.x * 64;
    const int Nb0 = blockIdx.y * 128;
    const int Mb = Mb0 + (w & 1) * 32;
    const int Nb = Nb0 + (w >> 1) * 64;
    const int mloc = (w & 1) * 32, nloc = (w >> 1) * 64;

    f32x4 acc[2][4];
    #pragma unroll
    for (int i = 0; i < 2; i++)
        #pragma unroll
        for (int j = 0; j < 4; j++) acc[i][j] = (f32x4){0.f, 0.f, 0.f, 0.f};

    const int sr = t >> 3, sc8 = (t & 7) * 8;

    for (int k0 = 0; k0 < DM; k0 += 64) {
        const int h = k0 >> 6;
        __syncthreads();
        #pragma unroll
        for (int i = 0; i < 2; i++) {
            int r = i * 32 + sr;
            *(uint4*)&As[r][sc8] = *(const uint4*)(A + (size_t)(Mb0 + r) * DM + k0 + sc8);
        }
        #pragma unroll
        for (int i = 0; i < 4; i++) {
            int r = i * 32 + sr;
            int m = Nb0 + r;
            int b = m >> 11, s = m & 2047;
            *(uint4*)&Bs[r][sc8] =
                *(const uint4*)(B + (size_t)(b * NH + h) * 131072 + (size_t)s * 64 + sc8);
        }
        __syncthreads();

        #pragma unroll
        for (int ks = 0; ks < 2; ks++) {
            const int kk = ks * 32 + quad * 8;
            bf16x8 a0 = *(const bf16x8*)&As[mloc + l16][kk];
            bf16x8 a1 = *(const bf16x8*)&As[mloc + 16 + l16][kk];
            #pragma unroll
            for (int nt = 0; nt < 4; nt++) {
                bf16x8 bf = *(const bf16x8*)&Bs[nloc + nt * 16 + l16][kk];
                acc[0][nt] = __builtin_amdgcn_mfma_f32_16x16x32_bf16(a0, bf, acc[0][nt], 0, 0, 0);
                acc[1][nt] = __builtin_amdgcn_mfma_f32_16x16x32_bf16(a1, bf, acc[1][nt], 0, 0, 0);
            }
        }
    }
    #pragma unroll
    for (int mt = 0; mt < 2; mt++) {
        int nf0 = Mb + mt * 16 + quad * 4;
        float4 bvv = *(const float4*)(bias + nf0);
        #pragma unroll
        for (int nt = 0; nt < 4; nt++) {
            int m = Nb + nt * 16 + l16;
            float4 o;
            o.x = acc[mt][nt][0] + bvv.x; o.y = acc[mt][nt][1] + bvv.y;
            o.z = acc[mt][nt][2] + bvv.z; o.w = acc[mt][nt][3] + bvv.w;
            *(float4*)(of32 + (size_t)m * DM + nf0) = o;
        }
    }
}

// ---- attention: 128 q-rows/block (4 waves x 32 rows), 32x32x16 MFMA,
// ---- swapped QK^T, in-register P, K/V fragments direct from global
// ---- (L2-resident, identical across waves) -- NO LDS, NO barriers. ----
__global__ __launch_bounds__(256) void attn_mfma(
    const u16* __restrict__ Q, const u16* __restrict__ K, const u16* __restrict__ VT,
    u16* __restrict__ O)
{
    const int t = threadIdx.x;
    const int w = t >> 6, lane = t & 63;
    const int l32 = lane & 31, h = lane >> 5;
    const int bh = blockIdx.y;
    const int q0 = blockIdx.x * 128;
    const size_t base = (size_t)bh * 131072;

    // Q fragment (B-operand of swapped QK): lane holds Q[q0+w*32+l32][ks*16+h*8 ..+7]
    const int qrow = q0 + w * 32 + l32;
    bf16x8 qf[4];
    #pragma unroll
    for (int ks = 0; ks < 4; ks++)
        qf[ks] = *(const bf16x8*)(Q + base + (size_t)qrow * 64 + ks * 16 + h * 8);

    const short onebf = (short)0x3F80;
    const bf16x8 ones = {onebf, onebf, onebf, onebf, onebf, onebf, onebf, onebf};

    f32x16 o[2], lacc;
    #pragma unroll
    for (int ht = 0; ht < 2; ht++)
        #pragma unroll
        for (int i = 0; i < 16; i++) o[ht][i] = 0.f;
    #pragma unroll
    for (int i = 0; i < 16; i++) lacc[i] = 0.f;

    // direct-global fragment base pointers (advance per kt tile)
    const u16* Kp0 = K  + base + (size_t)l32 * 64 + h * 8;          // kh=0 rows
    const u16* Kp1 = Kp0 + 32 * 64;                                  // kh=1 rows
    const u16* Vp0 = VT + base + (size_t)l32 * S_LEN + h * 8;        // ht=0 rows
    const u16* Vp1 = Vp0 + (size_t)32 * S_LEN;                       // ht=1 rows

    for (int kt = 0; kt < 32; kt++) {
        // K fragments: col offset ks*16 within this 64-k tile
        bf16x8 kf0[4], kf1[4];
        #pragma unroll
        for (int ks = 0; ks < 4; ks++) {
            kf0[ks] = *(const bf16x8*)(Kp0 + ks * 16);
            kf1[ks] = *(const bf16x8*)(Kp1 + ks * 16);
        }
        // V fragments: col offset kh*32 + j*16 within this tile
        bf16x8 vf0[4], vf1[4];   // [kh*2+j] for ht=0 / ht=1
        #pragma unroll
        for (int c = 0; c < 4; c++) {
            vf0[c] = *(const bf16x8*)(Vp0 + c * 16);
            vf1[c] = *(const bf16x8*)(Vp1 + c * 16);
        }

        #pragma unroll
        for (int kh = 0; kh < 2; kh++) {   // two 32-k subtiles of the 64-k tile
            // swapped QK^T: D[krow][qcol=l32] -- lane holds P[q=l32][16 k-rows]
            f32x16 s;
            #pragma unroll
            for (int i = 0; i < 16; i++) s[i] = 0.f;
            #pragma unroll
            for (int ks = 0; ks < 4; ks++) {
                bf16x8 kf = kh ? kf1[ks] : kf0[ks];
                s = __builtin_amdgcn_mfma_f32_32x32x16_bf16(kf, qf[ks], s, 0, 0, 0);
            }
            // P = 2^s (Q pre-scaled by 0.125*log2e); reg r, half h holds
            // k_local = (r&3) + 8*(r>>2) + 4*h
            float p[16];
            #pragma unroll
            for (int i = 0; i < 16; i++) p[i] = __builtin_amdgcn_exp2f(s[i]);
            // pack groups g=r>>2: A[g]=pk(p[4g],p[4g+1]), B[g]=pk(p[4g+2],p[4g+3])
            u32 A0 = pk_bf16(p[0],  p[1]),  B0 = pk_bf16(p[2],  p[3]);
            u32 A1 = pk_bf16(p[4],  p[5]),  B1 = pk_bf16(p[6],  p[7]);
            u32 A2 = pk_bf16(p[8],  p[9]),  B2 = pk_bf16(p[10], p[11]);
            u32 A3 = pk_bf16(p[12], p[13]), B3 = pk_bf16(p[14], p[15]);
            // redistribute: PV A-frag for kstep t needs group g=2t+h from both halves
            u32x2 sA0 = __builtin_amdgcn_permlane32_swap(A0, A1, false, false);
            u32x2 sB0 = __builtin_amdgcn_permlane32_swap(B0, B1, false, false);
            u32x2 sA1 = __builtin_amdgcn_permlane32_swap(A2, A3, false, false);
            u32x2 sB1 = __builtin_amdgcn_permlane32_swap(B2, B3, false, false);
            union { bf16x8 v; u32 wd[4]; } fr0, fr1;
            fr0.wd[0] = sA0.x; fr0.wd[1] = sB0.x; fr0.wd[2] = sA0.y; fr0.wd[3] = sB0.y;
            fr1.wd[0] = sA1.x; fr1.wd[1] = sB1.x; fr1.wd[2] = sA1.y; fr1.wd[3] = sB1.y;

            // row-sum (denominator): D-rows of lacc align with O rows
            lacc = __builtin_amdgcn_mfma_f32_32x32x16_bf16(fr0.v, ones, lacc, 0, 0, 0);
            lacc = __builtin_amdgcn_mfma_f32_32x32x16_bf16(fr1.v, ones, lacc, 0, 0, 0);

            // PV: O[q][hd] += P[q][k] * V[k][hd]
            o[0] = __builtin_amdgcn_mfma_f32_32x32x16_bf16(fr0.v, vf0[kh * 2 + 0], o[0], 0, 0, 0);
            o[0] = __builtin_amdgcn_mfma_f32_32x32x16_bf16(fr1.v, vf0[kh * 2 + 1], o[0], 0, 0, 0);
            o[1] = __builtin_amdgcn_mfma_f32_32x32x16_bf16(fr0.v, vf1[kh * 2 + 0], o[1], 0, 0, 0);
            o[1] = __builtin_amdgcn_mfma_f32_32x32x16_bf16(fr1.v, vf1[kh * 2 + 1], o[1], 0, 0, 0);
        }

        Kp0 += 64 * 64; Kp1 += 64 * 64;   // next 64 k-tokens
        Vp0 += 64;      Vp1 += 64;        // next 64 cols of V^T
    }

    // normalize + store: O row (reg r, half h) = (r&3) + 8*(r>>2) + 4*h
    float inv[16];
    #pragma unroll
    for (int r = 0; r < 16; r++) inv[r] = 1.0f / lacc[r];
    #pragma unroll
    for (int ht = 0; ht < 2; ht++)
        #pragma unroll
        for (int r = 0; r < 16; r++) {
            int q = q0 + w * 32 + (r & 3) + 8 * (r >> 2) + 4 * h;
            O[base + (size_t)q * 64 + ht * 32 + l32] = f2bf(o[ht][r] * inv[r]);
        }
}

extern "C" void kernel_launch(void* const* d_in, const int* in_sizes, int n_in,
                              void* d_out, int out_size, void* d_ws, size_t ws_size,
                              hipStream_t stream) {
    const float* x  = (const float*)d_in[0];
    const float* Wq = (const float*)d_in[1];
    const float* bq = (const float*)d_in[2];
    const float* Wk = (const float*)d_in[3];
    const float* bk = (const float*)d_in[4];
    const float* Wv = (const float*)d_in[5];
    const float* bv = (const float*)d_in[6];
    const float* Wo = (const float*)d_in[7];
    const float* bo = (const float*)d_in[8];
    float* out = (float*)d_out;

    // d_out as scratch during prep+proj (dead until final GEMM)
    u16* xbf = (u16*)d_out;
    u16* wqt = xbf + 4194304;
    u16* wkt = wqt + 1048576;
    u16* wvt = wkt + 1048576;

    u16* qws  = (u16*)d_ws;               // Q, later attnout (head layout)
    u16* kws  = qws + 4194304;            // K head layout; later Wo^T
    u16* vtws = kws + 4194304;            // V^T [bh][hd][s]
    u16* wot  = kws;

    prep_x<<<4096, 256, 0, stream>>>(x, xbf);
    prep_wt3<<<dim3(16, 16, 3), 256, 0, stream>>>(Wq, Wk, Wv, wqt, wkt, wvt);

    gemm_qkv<<<dim3(16, 32), 256, 0, stream>>>(wqt, wkt, wvt, xbf, bq, bk, bv,
                                               qws, kws, vtws);

    attn_mfma<<<dim3(16, 32), 256, 0, stream>>>(qws, kws, vtws, qws);

    prep_wt1<<<dim3(16, 16), 256, 0, stream>>>(Wo, wot);
    gemm_out<<<dim3(16, 32), 256, 0, stream>>>(wot, qws, bo, out);
}

// Round 5
// 198.940 us; speedup vs baseline: 1.3462x; 1.3462x over previous
//
#include <hip/hip_runtime.h>
#include <hip/hip_bf16.h>
#include <string.h>

// MHA B=2,S=2048,D=1024,H=16,Hd=64. Inputs fp32, output fp32.
// R23: (a) attn reverted EXACTLY to R21 (61.6us measured; R22's direct-
// global K/V was an L2-bandwidth regression -- staging amortizes L2 reads
// across waves, 4x traffic cut). (b) gemm_qkv restructured to z-split
// 128x128 tiles (blockIdx.z in {Q,K,V}): 32 MFMA vs 24 LDS ops per wave
// per K-step (was 24:30), 3 blocks/CU (was 2). gemm_out/preps unchanged.

#define DM 1024
#define S_LEN 2048
#define NH 16
#define HD 64

using u16 = unsigned short;
using u32 = unsigned int;

typedef short bf16x8 __attribute__((ext_vector_type(8)));
typedef float f32x4  __attribute__((ext_vector_type(4)));
typedef float f32x16 __attribute__((ext_vector_type(16)));
typedef unsigned int u32x2 __attribute__((ext_vector_type(2)));

__device__ __forceinline__ u16 f2bf(float f) {
    u32 i = __float_as_uint(f);
    u32 r = i + 0x7fffu + ((i >> 16) & 1u);  // RNE
    return (u16)(r >> 16);
}
__device__ __forceinline__ u32 pk_bf16(float a, float b) {  // low16=a, high16=b (RNE)
    __hip_bfloat162 h = __float22bfloat162_rn(float2{a, b});
    u32 r; memcpy(&r, &h, 4);
    return r;
}

// ---- prep: x fp32 -> bf16 ----
__global__ __launch_bounds__(256) void prep_x(const float* __restrict__ X, u16* __restrict__ out) {
    int i = (blockIdx.x * 256 + threadIdx.x) * 4;
    float4 v = *(const float4*)(X + i);
    *(uint2*)(out + i) = make_uint2(pk_bf16(v.x, v.y), pk_bf16(v.z, v.w));
}

// ---- prep: W fp32 [K][N] -> W^T bf16 [N][K] ----
__global__ __launch_bounds__(256) void prep_wt3(
    const float* __restrict__ W0, const float* __restrict__ W1, const float* __restrict__ W2,
    u16* __restrict__ T0, u16* __restrict__ T1, u16* __restrict__ T2)
{
    __shared__ u16 tile[64][72];
    const float* W = (blockIdx.z == 0) ? W0 : (blockIdx.z == 1) ? W1 : W2;
    u16* WT        = (blockIdx.z == 0) ? T0 : (blockIdx.z == 1) ? T1 : T2;
    const int t = threadIdx.x;
    const int n0 = blockIdx.x * 64, k0 = blockIdx.y * 64;
    #pragma unroll
    for (int it = 0; it < 4; it++) {
        int k = it * 16 + (t >> 4);
        int n = (t & 15) * 4;
        float4 v = *(const float4*)(W + (size_t)(k0 + k) * DM + n0 + n);
        tile[n + 0][k] = f2bf(v.x);
        tile[n + 1][k] = f2bf(v.y);
        tile[n + 2][k] = f2bf(v.z);
        tile[n + 3][k] = f2bf(v.w);
    }
    __syncthreads();
    int n = t >> 2, kg = (t & 3) * 16;
    uint4 a = *(const uint4*)&tile[n][kg];
    uint4 b = *(const uint4*)&tile[n][kg + 8];
    *(uint4*)(WT + (size_t)(n0 + n) * DM + k0 + kg)     = a;
    *(uint4*)(WT + (size_t)(n0 + n) * DM + k0 + kg + 8) = b;
}

__global__ __launch_bounds__(256) void prep_wt1(const float* __restrict__ W, u16* __restrict__ WT) {
    __shared__ u16 tile[64][72];
    const int t = threadIdx.x;
    const int n0 = blockIdx.x * 64, k0 = blockIdx.y * 64;
    #pragma unroll
    for (int it = 0; it < 4; it++) {
        int k = it * 16 + (t >> 4);
        int n = (t & 15) * 4;
        float4 v = *(const float4*)(W + (size_t)(k0 + k) * DM + n0 + n);
        tile[n + 0][k] = f2bf(v.x);
        tile[n + 1][k] = f2bf(v.y);
        tile[n + 2][k] = f2bf(v.z);
        tile[n + 3][k] = f2bf(v.w);
    }
    __syncthreads();
    int n = t >> 2, kg = (t & 3) * 16;
    uint4 a = *(const uint4*)&tile[n][kg];
    uint4 b = *(const uint4*)&tile[n][kg + 8];
    *(uint4*)(WT + (size_t)(n0 + n) * DM + k0 + kg)     = a;
    *(uint4*)(WT + (size_t)(n0 + n) * DM + k0 + kg + 8) = b;
}

// ---- QKV projection, z-split: blockIdx.z selects Q/K/V. 128x128 tile,
// ---- BK=64, 4 waves each computing 64x64. 3 blocks/CU. ----
__global__ __launch_bounds__(256, 3) void gemm_qkv_z(
    const u16* __restrict__ WQT, const u16* __restrict__ WKT, const u16* __restrict__ WVT,
    const u16* __restrict__ X,
    const float* __restrict__ bq, const float* __restrict__ bk, const float* __restrict__ bv,
    u16* __restrict__ outQ, u16* __restrict__ outK, u16* __restrict__ outVT)
{
    __shared__ u16 Ws[128][72];
    __shared__ u16 Xs[128][72];

    const int z = blockIdx.z;
    const u16* WT = (z == 0) ? WQT : (z == 1) ? WKT : WVT;

    const int t = threadIdx.x;
    const int w = t >> 6, lane = t & 63, quad = lane >> 4, l16 = lane & 15;
    const int Mb0 = blockIdx.x * 128;
    const int Nb0 = blockIdx.y * 128;
    const int mloc = (w & 1) * 64, nloc = (w >> 1) * 64;

    f32x4 acc[4][4];
    #pragma unroll
    for (int i = 0; i < 4; i++)
        #pragma unroll
        for (int j = 0; j < 4; j++) acc[i][j] = (f32x4){0.f, 0.f, 0.f, 0.f};

    const int sr = t >> 3, sc8 = (t & 7) * 8;

    for (int k0 = 0; k0 < DM; k0 += 64) {
        __syncthreads();
        #pragma unroll
        for (int i = 0; i < 4; i++) {
            int r = i * 32 + sr;
            *(uint4*)&Ws[r][sc8] = *(const uint4*)(WT + (size_t)(Mb0 + r) * DM + k0 + sc8);
            *(uint4*)&Xs[r][sc8] = *(const uint4*)(X  + (size_t)(Nb0 + r) * DM + k0 + sc8);
        }
        __syncthreads();

        #pragma unroll
        for (int ks = 0; ks < 2; ks++) {
            const int kk = ks * 32 + quad * 8;
            bf16x8 af[4], bf[4];
            #pragma unroll
            for (int mt = 0; mt < 4; mt++)
                af[mt] = *(const bf16x8*)&Ws[mloc + mt * 16 + l16][kk];
            #pragma unroll
            for (int nt = 0; nt < 4; nt++)
                bf[nt] = *(const bf16x8*)&Xs[nloc + nt * 16 + l16][kk];
            #pragma unroll
            for (int mt = 0; mt < 4; mt++)
                #pragma unroll
                for (int nt = 0; nt < 4; nt++)
                    acc[mt][nt] = __builtin_amdgcn_mfma_f32_16x16x32_bf16(af[mt], bf[nt], acc[mt][nt], 0, 0, 0);
        }
    }

    const float QS = 0.18033688f;  // 0.125 * log2(e): attn uses raw v_exp (2^x)
    if (z <= 1) {
        u16* outP = (z == 0) ? outQ : outK;
        const float* bias = (z == 0) ? bq : bk;
        const float scale = (z == 0) ? QS : 1.0f;
        #pragma unroll
        for (int mt = 0; mt < 4; mt++) {
            int nf0 = Mb0 + mloc + mt * 16 + quad * 4;
            int hh = nf0 >> 6, hd = nf0 & 63;
            float4 bb = *(const float4*)(bias + nf0);
            #pragma unroll
            for (int nt = 0; nt < 4; nt++) {
                int m = Nb0 + nloc + nt * 16 + l16;
                int b = m >> 11, s = m & 2047;
                size_t idx = (size_t)(b * NH + hh) * 131072 + (size_t)s * 64 + hd;
                *(uint2*)(outP + idx) = make_uint2(
                    pk_bf16((acc[mt][nt][0] + bb.x) * scale, (acc[mt][nt][1] + bb.y) * scale),
                    pk_bf16((acc[mt][nt][2] + bb.z) * scale, (acc[mt][nt][3] + bb.w) * scale));
            }
        }
    } else {
        #pragma unroll
        for (int mt = 0; mt < 4; mt++) {
            #pragma unroll
            for (int r = 0; r < 4; r++) {
                int nf = Mb0 + mloc + mt * 16 + quad * 4 + r;
                int hh = nf >> 6, hd = nf & 63;
                float bb = bv[nf];
                #pragma unroll
                for (int nt = 0; nt < 4; nt++) {
                    int m = Nb0 + nloc + nt * 16 + l16;
                    int b = m >> 11, s = m & 2047;
                    outVT[(size_t)(b * NH + hh) * 131072 + (size_t)hd * S_LEN + s]
                        = f2bf(acc[mt][nt][r] + bb);
                }
            }
        }
    }
}

// ---- out GEMM, LDS-staged. Block: 64 feat x 128 tok, BK=64. ----
__global__ __launch_bounds__(256) void gemm_out(
    const u16* __restrict__ A, const u16* __restrict__ B,
    const float* __restrict__ bias, float* __restrict__ of32)
{
    __shared__ u16 As[64][72];
    __shared__ u16 Bs[128][72];

    const int t = threadIdx.x;
    const int w = t >> 6, lane = t & 63, quad = lane >> 4, l16 = lane & 15;
    const int Mb0 = blockIdx.x * 64;
    const int Nb0 = blockIdx.y * 128;
    const int Mb = Mb0 + (w & 1) * 32;
    const int Nb = Nb0 + (w >> 1) * 64;
    const int mloc = (w & 1) * 32, nloc = (w >> 1) * 64;

    f32x4 acc[2][4];
    #pragma unroll
    for (int i = 0; i < 2; i++)
        #pragma unroll
        for (int j = 0; j < 4; j++) acc[i][j] = (f32x4){0.f, 0.f, 0.f, 0.f};

    const int sr = t >> 3, sc8 = (t & 7) * 8;

    for (int k0 = 0; k0 < DM; k0 += 64) {
        const int h = k0 >> 6;
        __syncthreads();
        #pragma unroll
        for (int i = 0; i < 2; i++) {
            int r = i * 32 + sr;
            *(uint4*)&As[r][sc8] = *(const uint4*)(A + (size_t)(Mb0 + r) * DM + k0 + sc8);
        }
        #pragma unroll
        for (int i = 0; i < 4; i++) {
            int r = i * 32 + sr;
            int m = Nb0 + r;
            int b = m >> 11, s = m & 2047;
            *(uint4*)&Bs[r][sc8] =
                *(const uint4*)(B + (size_t)(b * NH + h) * 131072 + (size_t)s * 64 + sc8);
        }
        __syncthreads();

        #pragma unroll
        for (int ks = 0; ks < 2; ks++) {
            const int kk = ks * 32 + quad * 8;
            bf16x8 a0 = *(const bf16x8*)&As[mloc + l16][kk];
            bf16x8 a1 = *(const bf16x8*)&As[mloc + 16 + l16][kk];
            #pragma unroll
            for (int nt = 0; nt < 4; nt++) {
                bf16x8 bf = *(const bf16x8*)&Bs[nloc + nt * 16 + l16][kk];
                acc[0][nt] = __builtin_amdgcn_mfma_f32_16x16x32_bf16(a0, bf, acc[0][nt], 0, 0, 0);
                acc[1][nt] = __builtin_amdgcn_mfma_f32_16x16x32_bf16(a1, bf, acc[1][nt], 0, 0, 0);
            }
        }
    }
    #pragma unroll
    for (int mt = 0; mt < 2; mt++) {
        int nf0 = Mb + mt * 16 + quad * 4;
        float4 bvv = *(const float4*)(bias + nf0);
        #pragma unroll
        for (int nt = 0; nt < 4; nt++) {
            int m = Nb + nt * 16 + l16;
            float4 o;
            o.x = acc[mt][nt][0] + bvv.x; o.y = acc[mt][nt][1] + bvv.y;
            o.z = acc[mt][nt][2] + bvv.z; o.w = acc[mt][nt][3] + bvv.w;
            *(float4*)(of32 + (size_t)m * DM + nf0) = o;
        }
    }
}

// ---- attention: 128 q-rows/block (4 waves x 32 rows), 32x32x16 MFMA,
// ---- swapped QK^T, in-register P, dbuf K/V LDS + reg prefetch,
// ---- grid 16x32 = 2 blocks/CU (independent barrier groups). ----
__global__ __launch_bounds__(256) void attn_mfma(
    const u16* __restrict__ Q, const u16* __restrict__ K, const u16* __restrict__ VT,
    u16* __restrict__ O)
{
    __shared__ u16 Ks[2][64][72];
    __shared__ u16 Vs[2][64][72];

    const int t = threadIdx.x;
    const int w = t >> 6, lane = t & 63;
    const int l32 = lane & 31, h = lane >> 5;
    const int bh = blockIdx.y;
    const int q0 = blockIdx.x * 128;
    const size_t base = (size_t)bh * 131072;

    // Q fragment (B-operand of swapped QK): lane holds Q[q0+w*32+l32][ks*16+h*8 ..+7]
    const int qrow = q0 + w * 32 + l32;
    bf16x8 qf[4];
    #pragma unroll
    for (int ks = 0; ks < 4; ks++)
        qf[ks] = *(const bf16x8*)(Q + base + (size_t)qrow * 64 + ks * 16 + h * 8);

    const short onebf = (short)0x3F80;
    const bf16x8 ones = {onebf, onebf, onebf, onebf, onebf, onebf, onebf, onebf};

    f32x16 o[2], lacc;
    #pragma unroll
    for (int ht = 0; ht < 2; ht++)
        #pragma unroll
        for (int i = 0; i < 16; i++) o[ht][i] = 0.f;
    #pragma unroll
    for (int i = 0; i < 16; i++) lacc[i] = 0.f;

    // staging: 256 threads cover one [64][64]-u16 tile in 2 chunks of 16 B
    const int sr = t >> 3;            // 0..31
    const int sc8 = (t & 7) * 8;      // u16 col
    const u16* Kg = K + base;
    const u16* Vg = VT + base;

    #pragma unroll
    for (int i = 0; i < 2; i++) {
        int r = i * 32 + sr;
        *(uint4*)&Ks[0][r][sc8] = *(const uint4*)(Kg + (size_t)r * 64 + sc8);
        *(uint4*)&Vs[0][r][sc8] = *(const uint4*)(Vg + (size_t)r * S_LEN + sc8);
    }
    __syncthreads();

    for (int kt = 0; kt < 32; kt++) {
        const int cur = kt & 1;
        uint4 kreg[2], vreg[2];
        if (kt < 31) {
            #pragma unroll
            for (int i = 0; i < 2; i++) {
                int r = i * 32 + sr;
                kreg[i] = *(const uint4*)(Kg + (size_t)((kt + 1) * 64 + r) * 64 + sc8);
                vreg[i] = *(const uint4*)(Vg + (size_t)r * S_LEN + (kt + 1) * 64 + sc8);
            }
        }

        #pragma unroll
        for (int kh = 0; kh < 2; kh++) {   // two 32-k subtiles of the 64-k tile
            // swapped QK^T: D[krow][qcol=l32] -- lane holds P[q=l32][16 k-rows]
            f32x16 s;
            #pragma unroll
            for (int i = 0; i < 16; i++) s[i] = 0.f;
            #pragma unroll
            for (int ks = 0; ks < 4; ks++) {
                bf16x8 kf = *(const bf16x8*)&Ks[cur][kh * 32 + l32][ks * 16 + h * 8];
                s = __builtin_amdgcn_mfma_f32_32x32x16_bf16(kf, qf[ks], s, 0, 0, 0);
            }
            // P = 2^s (Q pre-scaled by 0.125*log2e); reg r, half h holds
            // k_local = (r&3) + 8*(r>>2) + 4*h
            float p[16];
            #pragma unroll
            for (int i = 0; i < 16; i++) p[i] = __builtin_amdgcn_exp2f(s[i]);
            // pack groups g=r>>2: A[g]=pk(p[4g],p[4g+1]), B[g]=pk(p[4g+2],p[4g+3])
            u32 A0 = pk_bf16(p[0],  p[1]),  B0 = pk_bf16(p[2],  p[3]);
            u32 A1 = pk_bf16(p[4],  p[5]),  B1 = pk_bf16(p[6],  p[7]);
            u32 A2 = pk_bf16(p[8],  p[9]),  B2 = pk_bf16(p[10], p[11]);
            u32 A3 = pk_bf16(p[12], p[13]), B3 = pk_bf16(p[14], p[15]);
            // redistribute: PV A-frag for kstep t needs group g=2t+h from both halves
            u32x2 sA0 = __builtin_amdgcn_permlane32_swap(A0, A1, false, false);
            u32x2 sB0 = __builtin_amdgcn_permlane32_swap(B0, B1, false, false);
            u32x2 sA1 = __builtin_amdgcn_permlane32_swap(A2, A3, false, false);
            u32x2 sB1 = __builtin_amdgcn_permlane32_swap(B2, B3, false, false);
            union { bf16x8 v; u32 wd[4]; } fr0, fr1;
            fr0.wd[0] = sA0.x; fr0.wd[1] = sB0.x; fr0.wd[2] = sA0.y; fr0.wd[3] = sB0.y;
            fr1.wd[0] = sA1.x; fr1.wd[1] = sB1.x; fr1.wd[2] = sA1.y; fr1.wd[3] = sB1.y;

            // row-sum (denominator): D-rows of lacc align with O rows
            lacc = __builtin_amdgcn_mfma_f32_32x32x16_bf16(fr0.v, ones, lacc, 0, 0, 0);
            lacc = __builtin_amdgcn_mfma_f32_32x32x16_bf16(fr1.v, ones, lacc, 0, 0, 0);

            // PV: O[q][hd] += P[q][k] * V[k][hd]
            #pragma unroll
            for (int ht = 0; ht < 2; ht++) {
                bf16x8 vf0 = *(const bf16x8*)&Vs[cur][ht * 32 + l32][kh * 32 + h * 8];
                o[ht] = __builtin_amdgcn_mfma_f32_32x32x16_bf16(fr0.v, vf0, o[ht], 0, 0, 0);
                bf16x8 vf1 = *(const bf16x8*)&Vs[cur][ht * 32 + l32][kh * 32 + 16 + h * 8];
                o[ht] = __builtin_amdgcn_mfma_f32_32x32x16_bf16(fr1.v, vf1, o[ht], 0, 0, 0);
            }
        }

        if (kt < 31) {
            #pragma unroll
            for (int i = 0; i < 2; i++) {
                int r = i * 32 + sr;
                *(uint4*)&Ks[cur ^ 1][r][sc8] = kreg[i];
                *(uint4*)&Vs[cur ^ 1][r][sc8] = vreg[i];
            }
        }
        __syncthreads();
    }

    // normalize + store: O row (reg r, half h) = (r&3) + 8*(r>>2) + 4*h
    float inv[16];
    #pragma unroll
    for (int r = 0; r < 16; r++) inv[r] = 1.0f / lacc[r];
    #pragma unroll
    for (int ht = 0; ht < 2; ht++)
        #pragma unroll
        for (int r = 0; r < 16; r++) {
            int q = q0 + w * 32 + (r & 3) + 8 * (r >> 2) + 4 * h;
            O[base + (size_t)q * 64 + ht * 32 + l32] = f2bf(o[ht][r] * inv[r]);
        }
}

extern "C" void kernel_launch(void* const* d_in, const int* in_sizes, int n_in,
                              void* d_out, int out_size, void* d_ws, size_t ws_size,
                              hipStream_t stream) {
    const float* x  = (const float*)d_in[0];
    const float* Wq = (const float*)d_in[1];
    const float* bq = (const float*)d_in[2];
    const float* Wk = (const float*)d_in[3];
    const float* bk = (const float*)d_in[4];
    const float* Wv = (const float*)d_in[5];
    const float* bv = (const float*)d_in[6];
    const float* Wo = (const float*)d_in[7];
    const float* bo = (const float*)d_in[8];
    float* out = (float*)d_out;

    // d_out as scratch during prep+proj (dead until final GEMM)
    u16* xbf = (u16*)d_out;
    u16* wqt = xbf + 4194304;
    u16* wkt = wqt + 1048576;
    u16* wvt = wkt + 1048576;

    u16* qws  = (u16*)d_ws;               // Q, later attnout (head layout)
    u16* kws  = qws + 4194304;            // K head layout; later Wo^T
    u16* vtws = kws + 4194304;            // V^T [bh][hd][s]
    u16* wot  = kws;

    prep_x<<<4096, 256, 0, stream>>>(x, xbf);
    prep_wt3<<<dim3(16, 16, 3), 256, 0, stream>>>(Wq, Wk, Wv, wqt, wkt, wvt);

    gemm_qkv_z<<<dim3(8, 32, 3), 256, 0, stream>>>(wqt, wkt, wvt, xbf, bq, bk, bv,
                                                   qws, kws, vtws);

    attn_mfma<<<dim3(16, 32), 256, 0, stream>>>(qws, kws, vtws, qws);

    prep_wt1<<<dim3(16, 16), 256, 0, stream>>>(Wo, wot);
    gemm_out<<<dim3(16, 32), 256, 0, stream>>>(wot, qws, bo, out);
}

// Round 7
// 197.816 us; speedup vs baseline: 1.3538x; 1.0057x over previous
//
#include <hip/hip_runtime.h>
#include <hip/hip_bf16.h>
#include <string.h>

// MHA B=2,S=2048,D=1024,H=16,Hd=64. Inputs fp32, output fp32.
// R24 (resubmit; R6 bench was a GPU-acquisition infra failure, kernel
// never ran). attn in-block split-K: work decomposition (2048 waves)
// capped occupancy at 2 waves/SIMD -- every pipe <=50% busy (MfmaUtil 28,
// VALU 47, DS 43). Now 8 waves/block: waves 0-3 do k-tiles 0-15, waves
// 4-7 do k-tiles 16-31 (raw-exp2 softmax => partials combine additively,
// LDS reduction at end, no rescale). 73.7KB LDS, 2 blocks/CU = 16
// waves/CU (4/SIMD) -- doubles per-pipe occupancy, VALU/TRANS pipe
// ~saturates. GEMMs/preps unchanged from R23.

#define DM 1024
#define S_LEN 2048
#define NH 16
#define HD 64

using u16 = unsigned short;
using u32 = unsigned int;

typedef short bf16x8 __attribute__((ext_vector_type(8)));
typedef float f32x4  __attribute__((ext_vector_type(4)));
typedef float f32x16 __attribute__((ext_vector_type(16)));
typedef unsigned int u32x2 __attribute__((ext_vector_type(2)));

__device__ __forceinline__ u16 f2bf(float f) {
    u32 i = __float_as_uint(f);
    u32 r = i + 0x7fffu + ((i >> 16) & 1u);  // RNE
    return (u16)(r >> 16);
}
__device__ __forceinline__ u32 pk_bf16(float a, float b) {  // low16=a, high16=b (RNE)
    __hip_bfloat162 h = __float22bfloat162_rn(float2{a, b});
    u32 r; memcpy(&r, &h, 4);
    return r;
}

// ---- prep: x fp32 -> bf16 ----
__global__ __launch_bounds__(256) void prep_x(const float* __restrict__ X, u16* __restrict__ out) {
    int i = (blockIdx.x * 256 + threadIdx.x) * 4;
    float4 v = *(const float4*)(X + i);
    *(uint2*)(out + i) = make_uint2(pk_bf16(v.x, v.y), pk_bf16(v.z, v.w));
}

// ---- prep: W fp32 [K][N] -> W^T bf16 [N][K] ----
__global__ __launch_bounds__(256) void prep_wt3(
    const float* __restrict__ W0, const float* __restrict__ W1, const float* __restrict__ W2,
    u16* __restrict__ T0, u16* __restrict__ T1, u16* __restrict__ T2)
{
    __shared__ u16 tile[64][72];
    const float* W = (blockIdx.z == 0) ? W0 : (blockIdx.z == 1) ? W1 : W2;
    u16* WT        = (blockIdx.z == 0) ? T0 : (blockIdx.z == 1) ? T1 : T2;
    const int t = threadIdx.x;
    const int n0 = blockIdx.x * 64, k0 = blockIdx.y * 64;
    #pragma unroll
    for (int it = 0; it < 4; it++) {
        int k = it * 16 + (t >> 4);
        int n = (t & 15) * 4;
        float4 v = *(const float4*)(W + (size_t)(k0 + k) * DM + n0 + n);
        tile[n + 0][k] = f2bf(v.x);
        tile[n + 1][k] = f2bf(v.y);
        tile[n + 2][k] = f2bf(v.z);
        tile[n + 3][k] = f2bf(v.w);
    }
    __syncthreads();
    int n = t >> 2, kg = (t & 3) * 16;
    uint4 a = *(const uint4*)&tile[n][kg];
    uint4 b = *(const uint4*)&tile[n][kg + 8];
    *(uint4*)(WT + (size_t)(n0 + n) * DM + k0 + kg)     = a;
    *(uint4*)(WT + (size_t)(n0 + n) * DM + k0 + kg + 8) = b;
}

__global__ __launch_bounds__(256) void prep_wt1(const float* __restrict__ W, u16* __restrict__ WT) {
    __shared__ u16 tile[64][72];
    const int t = threadIdx.x;
    const int n0 = blockIdx.x * 64, k0 = blockIdx.y * 64;
    #pragma unroll
    for (int it = 0; it < 4; it++) {
        int k = it * 16 + (t >> 4);
        int n = (t & 15) * 4;
        float4 v = *(const float4*)(W + (size_t)(k0 + k) * DM + n0 + n);
        tile[n + 0][k] = f2bf(v.x);
        tile[n + 1][k] = f2bf(v.y);
        tile[n + 2][k] = f2bf(v.z);
        tile[n + 3][k] = f2bf(v.w);
    }
    __syncthreads();
    int n = t >> 2, kg = (t & 3) * 16;
    uint4 a = *(const uint4*)&tile[n][kg];
    uint4 b = *(const uint4*)&tile[n][kg + 8];
    *(uint4*)(WT + (size_t)(n0 + n) * DM + k0 + kg)     = a;
    *(uint4*)(WT + (size_t)(n0 + n) * DM + k0 + kg + 8) = b;
}

// ---- QKV projection, z-split: blockIdx.z selects Q/K/V. 128x128 tile,
// ---- BK=64, 4 waves each computing 64x64. 3 blocks/CU. ----
__global__ __launch_bounds__(256, 3) void gemm_qkv_z(
    const u16* __restrict__ WQT, const u16* __restrict__ WKT, const u16* __restrict__ WVT,
    const u16* __restrict__ X,
    const float* __restrict__ bq, const float* __restrict__ bk, const float* __restrict__ bv,
    u16* __restrict__ outQ, u16* __restrict__ outK, u16* __restrict__ outVT)
{
    __shared__ u16 Ws[128][72];
    __shared__ u16 Xs[128][72];

    const int z = blockIdx.z;
    const u16* WT = (z == 0) ? WQT : (z == 1) ? WKT : WVT;

    const int t = threadIdx.x;
    const int w = t >> 6, lane = t & 63, quad = lane >> 4, l16 = lane & 15;
    const int Mb0 = blockIdx.x * 128;
    const int Nb0 = blockIdx.y * 128;
    const int mloc = (w & 1) * 64, nloc = (w >> 1) * 64;

    f32x4 acc[4][4];
    #pragma unroll
    for (int i = 0; i < 4; i++)
        #pragma unroll
        for (int j = 0; j < 4; j++) acc[i][j] = (f32x4){0.f, 0.f, 0.f, 0.f};

    const int sr = t >> 3, sc8 = (t & 7) * 8;

    for (int k0 = 0; k0 < DM; k0 += 64) {
        __syncthreads();
        #pragma unroll
        for (int i = 0; i < 4; i++) {
            int r = i * 32 + sr;
            *(uint4*)&Ws[r][sc8] = *(const uint4*)(WT + (size_t)(Mb0 + r) * DM + k0 + sc8);
            *(uint4*)&Xs[r][sc8] = *(const uint4*)(X  + (size_t)(Nb0 + r) * DM + k0 + sc8);
        }
        __syncthreads();

        #pragma unroll
        for (int ks = 0; ks < 2; ks++) {
            const int kk = ks * 32 + quad * 8;
            bf16x8 af[4], bf[4];
            #pragma unroll
            for (int mt = 0; mt < 4; mt++)
                af[mt] = *(const bf16x8*)&Ws[mloc + mt * 16 + l16][kk];
            #pragma unroll
            for (int nt = 0; nt < 4; nt++)
                bf[nt] = *(const bf16x8*)&Xs[nloc + nt * 16 + l16][kk];
            #pragma unroll
            for (int mt = 0; mt < 4; mt++)
                #pragma unroll
                for (int nt = 0; nt < 4; nt++)
                    acc[mt][nt] = __builtin_amdgcn_mfma_f32_16x16x32_bf16(af[mt], bf[nt], acc[mt][nt], 0, 0, 0);
        }
    }

    const float QS = 0.18033688f;  // 0.125 * log2(e): attn uses raw v_exp (2^x)
    if (z <= 1) {
        u16* outP = (z == 0) ? outQ : outK;
        const float* bias = (z == 0) ? bq : bk;
        const float scale = (z == 0) ? QS : 1.0f;
        #pragma unroll
        for (int mt = 0; mt < 4; mt++) {
            int nf0 = Mb0 + mloc + mt * 16 + quad * 4;
            int hh = nf0 >> 6, hd = nf0 & 63;
            float4 bb = *(const float4*)(bias + nf0);
            #pragma unroll
            for (int nt = 0; nt < 4; nt++) {
                int m = Nb0 + nloc + nt * 16 + l16;
                int b = m >> 11, s = m & 2047;
                size_t idx = (size_t)(b * NH + hh) * 131072 + (size_t)s * 64 + hd;
                *(uint2*)(outP + idx) = make_uint2(
                    pk_bf16((acc[mt][nt][0] + bb.x) * scale, (acc[mt][nt][1] + bb.y) * scale),
                    pk_bf16((acc[mt][nt][2] + bb.z) * scale, (acc[mt][nt][3] + bb.w) * scale));
            }
        }
    } else {
        #pragma unroll
        for (int mt = 0; mt < 4; mt++) {
            #pragma unroll
            for (int r = 0; r < 4; r++) {
                int nf = Mb0 + mloc + mt * 16 + quad * 4 + r;
                int hh = nf >> 6, hd = nf & 63;
                float bb = bv[nf];
                #pragma unroll
                for (int nt = 0; nt < 4; nt++) {
                    int m = Nb0 + nloc + nt * 16 + l16;
                    int b = m >> 11, s = m & 2047;
                    outVT[(size_t)(b * NH + hh) * 131072 + (size_t)hd * S_LEN + s]
                        = f2bf(acc[mt][nt][r] + bb);
                }
            }
        }
    }
}

// ---- out GEMM, LDS-staged. Block: 64 feat x 128 tok, BK=64. ----
__global__ __launch_bounds__(256) void gemm_out(
    const u16* __restrict__ A, const u16* __restrict__ B,
    const float* __restrict__ bias, float* __restrict__ of32)
{
    __shared__ u16 As[64][72];
    __shared__ u16 Bs[128][72];

    const int t = threadIdx.x;
    const int w = t >> 6, lane = t & 63, quad = lane >> 4, l16 = lane & 15;
    const int Mb0 = blockIdx.x * 64;
    const int Nb0 = blockIdx.y * 128;
    const int Mb = Mb0 + (w & 1) * 32;
    const int Nb = Nb0 + (w >> 1) * 64;
    const int mloc = (w & 1) * 32, nloc = (w >> 1) * 64;

    f32x4 acc[2][4];
    #pragma unroll
    for (int i = 0; i < 2; i++)
        #pragma unroll
        for (int j = 0; j < 4; j++) acc[i][j] = (f32x4){0.f, 0.f, 0.f, 0.f};

    const int sr = t >> 3, sc8 = (t & 7) * 8;

    for (int k0 = 0; k0 < DM; k0 += 64) {
        const int h = k0 >> 6;
        __syncthreads();
        #pragma unroll
        for (int i = 0; i < 2; i++) {
            int r = i * 32 + sr;
            *(uint4*)&As[r][sc8] = *(const uint4*)(A + (size_t)(Mb0 + r) * DM + k0 + sc8);
        }
        #pragma unroll
        for (int i = 0; i < 4; i++) {
            int r = i * 32 + sr;
            int m = Nb0 + r;
            int b = m >> 11, s = m & 2047;
            *(uint4*)&Bs[r][sc8] =
                *(const uint4*)(B + (size_t)(b * NH + h) * 131072 + (size_t)s * 64 + sc8);
        }
        __syncthreads();

        #pragma unroll
        for (int ks = 0; ks < 2; ks++) {
            const int kk = ks * 32 + quad * 8;
            bf16x8 a0 = *(const bf16x8*)&As[mloc + l16][kk];
            bf16x8 a1 = *(const bf16x8*)&As[mloc + 16 + l16][kk];
            #pragma unroll
            for (int nt = 0; nt < 4; nt++) {
                bf16x8 bf = *(const bf16x8*)&Bs[nloc + nt * 16 + l16][kk];
                acc[0][nt] = __builtin_amdgcn_mfma_f32_16x16x32_bf16(a0, bf, acc[0][nt], 0, 0, 0);
                acc[1][nt] = __builtin_amdgcn_mfma_f32_16x16x32_bf16(a1, bf, acc[1][nt], 0, 0, 0);
            }
        }
    }
    #pragma unroll
    for (int mt = 0; mt < 2; mt++) {
        int nf0 = Mb + mt * 16 + quad * 4;
        float4 bvv = *(const float4*)(bias + nf0);
        #pragma unroll
        for (int nt = 0; nt < 4; nt++) {
            int m = Nb + nt * 16 + l16;
            float4 o;
            o.x = acc[mt][nt][0] + bvv.x; o.y = acc[mt][nt][1] + bvv.y;
            o.z = acc[mt][nt][2] + bvv.z; o.w = acc[mt][nt][3] + bvv.w;
            *(float4*)(of32 + (size_t)m * DM + nf0) = o;
        }
    }
}

// ---- attention: in-block split-K. 8 waves: waves 0-3 k-tiles [0,16),
// ---- waves 4-7 k-tiles [16,32), same 128 q-rows. 32x32 MFMA, swapped
// ---- QK^T, in-register P, dbuf K/V LDS per half, additive partial
// ---- combine via LDS (raw-exp2 softmax, no max -> no rescale). ----
__global__ __launch_bounds__(512, 4) void attn_mfma(
    const u16* __restrict__ Q, const u16* __restrict__ K, const u16* __restrict__ VT,
    u16* __restrict__ O)
{
    // [KV][half][buf][row][col] ; reused as f32 reduction region at the end
    __shared__ __align__(64) u16 smem[2][2][2][64][72];

    const int t = threadIdx.x;
    const int w = t >> 6, lane = t & 63;
    const int wq = w & 3, half = w >> 2;
    const int l32 = lane & 31, h = lane >> 5;
    const int bh = blockIdx.y;
    const int q0 = blockIdx.x * 128;
    const size_t base = (size_t)bh * 131072;

    // Q fragment (B-operand of swapped QK): lane holds Q[q0+wq*32+l32][ks*16+h*8 ..+7]
    const int qrow = q0 + wq * 32 + l32;
    bf16x8 qf[4];
    #pragma unroll
    for (int ks = 0; ks < 4; ks++)
        qf[ks] = *(const bf16x8*)(Q + base + (size_t)qrow * 64 + ks * 16 + h * 8);

    const short onebf = (short)0x3F80;
    const bf16x8 ones = {onebf, onebf, onebf, onebf, onebf, onebf, onebf, onebf};

    f32x16 o[2], lacc;
    #pragma unroll
    for (int ht = 0; ht < 2; ht++)
        #pragma unroll
        for (int i = 0; i < 16; i++) o[ht][i] = 0.f;
    #pragma unroll
    for (int i = 0; i < 16; i++) lacc[i] = 0.f;

    // staging: 512 threads x 16B cover one [64][64]-u16 tile per inst
    const int sr = t >> 3;            // 0..63
    const int sc8 = (t & 7) * 8;      // u16 col
    const u16* Kg = K + base;
    const u16* Vg = VT + base;

    // prologue: tiles 0 (half0) and 16 (half1) -> buf 0
    *(uint4*)&smem[0][0][0][sr][sc8] = *(const uint4*)(Kg + (size_t)sr * 64 + sc8);
    *(uint4*)&smem[0][1][0][sr][sc8] = *(const uint4*)(Kg + (size_t)(16 * 64 + sr) * 64 + sc8);
    *(uint4*)&smem[1][0][0][sr][sc8] = *(const uint4*)(Vg + (size_t)sr * S_LEN + sc8);
    *(uint4*)&smem[1][1][0][sr][sc8] = *(const uint4*)(Vg + (size_t)sr * S_LEN + 16 * 64 + sc8);
    __syncthreads();

    for (int it = 0; it < 16; it++) {
        const int cur = it & 1;
        uint4 kra, krb, vra, vrb;
        if (it < 15) {
            kra = *(const uint4*)(Kg + (size_t)((it + 1) * 64 + sr) * 64 + sc8);
            krb = *(const uint4*)(Kg + (size_t)((it + 17) * 64 + sr) * 64 + sc8);
            vra = *(const uint4*)(Vg + (size_t)sr * S_LEN + (it + 1) * 64 + sc8);
            vrb = *(const uint4*)(Vg + (size_t)sr * S_LEN + (it + 17) * 64 + sc8);
        }

        const u16 (*Ksc)[72] = smem[0][half][cur];
        const u16 (*Vsc)[72] = smem[1][half][cur];

        #pragma unroll
        for (int kh = 0; kh < 2; kh++) {   // two 32-k subtiles of the 64-k tile
            // swapped QK^T: D[krow][qcol=l32] -- lane holds P[q=l32][16 k-rows]
            f32x16 s;
            #pragma unroll
            for (int i = 0; i < 16; i++) s[i] = 0.f;
            #pragma unroll
            for (int ks = 0; ks < 4; ks++) {
                bf16x8 kf = *(const bf16x8*)&Ksc[kh * 32 + l32][ks * 16 + h * 8];
                s = __builtin_amdgcn_mfma_f32_32x32x16_bf16(kf, qf[ks], s, 0, 0, 0);
            }
            // P = 2^s (Q pre-scaled by 0.125*log2e); reg r, half h holds
            // k_local = (r&3) + 8*(r>>2) + 4*h
            float p[16];
            #pragma unroll
            for (int i = 0; i < 16; i++) p[i] = __builtin_amdgcn_exp2f(s[i]);
            u32 A0 = pk_bf16(p[0],  p[1]),  B0 = pk_bf16(p[2],  p[3]);
            u32 A1 = pk_bf16(p[4],  p[5]),  B1 = pk_bf16(p[6],  p[7]);
            u32 A2 = pk_bf16(p[8],  p[9]),  B2 = pk_bf16(p[10], p[11]);
            u32 A3 = pk_bf16(p[12], p[13]), B3 = pk_bf16(p[14], p[15]);
            u32x2 sA0 = __builtin_amdgcn_permlane32_swap(A0, A1, false, false);
            u32x2 sB0 = __builtin_amdgcn_permlane32_swap(B0, B1, false, false);
            u32x2 sA1 = __builtin_amdgcn_permlane32_swap(A2, A3, false, false);
            u32x2 sB1 = __builtin_amdgcn_permlane32_swap(B2, B3, false, false);
            union { bf16x8 v; u32 wd[4]; } fr0, fr1;
            fr0.wd[0] = sA0.x; fr0.wd[1] = sB0.x; fr0.wd[2] = sA0.y; fr0.wd[3] = sB0.y;
            fr1.wd[0] = sA1.x; fr1.wd[1] = sB1.x; fr1.wd[2] = sA1.y; fr1.wd[3] = sB1.y;

            // row-sum (denominator): D-rows of lacc align with O rows
            lacc = __builtin_amdgcn_mfma_f32_32x32x16_bf16(fr0.v, ones, lacc, 0, 0, 0);
            lacc = __builtin_amdgcn_mfma_f32_32x32x16_bf16(fr1.v, ones, lacc, 0, 0, 0);

            // PV: O[q][hd] += P[q][k] * V[k][hd]
            #pragma unroll
            for (int ht = 0; ht < 2; ht++) {
                bf16x8 vf0 = *(const bf16x8*)&Vsc[ht * 32 + l32][kh * 32 + h * 8];
                o[ht] = __builtin_amdgcn_mfma_f32_32x32x16_bf16(fr0.v, vf0, o[ht], 0, 0, 0);
                bf16x8 vf1 = *(const bf16x8*)&Vsc[ht * 32 + l32][kh * 32 + 16 + h * 8];
                o[ht] = __builtin_amdgcn_mfma_f32_32x32x16_bf16(fr1.v, vf1, o[ht], 0, 0, 0);
            }
        }

        if (it < 15) {
            *(uint4*)&smem[0][0][cur ^ 1][sr][sc8] = kra;
            *(uint4*)&smem[0][1][cur ^ 1][sr][sc8] = krb;
            *(uint4*)&smem[1][0][cur ^ 1][sr][sc8] = vra;
            *(uint4*)&smem[1][1][cur ^ 1][sr][sc8] = vrb;
        }
        __syncthreads();
    }

    // ---- cross-half reduction: half1 writes partials, half0 combines ----
    // layout: red[(chunk*4+wq)*16 + i][lane] -- lane-contiguous, conflict-free
    float* red = (float*)&smem[0][0][0][0][0];
    if (half) {
        #pragma unroll
        for (int i = 0; i < 16; i++) {
            red[((0 + wq) * 16 + i) * 64 + lane] = o[0][i];
            red[((4 + wq) * 16 + i) * 64 + lane] = o[1][i];
            red[((8 + wq) * 16 + i) * 64 + lane] = lacc[i];
        }
    }
    __syncthreads();
    if (!half) {
        #pragma unroll
        for (int i = 0; i < 16; i++) {
            o[0][i] += red[((0 + wq) * 16 + i) * 64 + lane];
            o[1][i] += red[((4 + wq) * 16 + i) * 64 + lane];
            lacc[i] += red[((8 + wq) * 16 + i) * 64 + lane];
        }
        float inv[16];
        #pragma unroll
        for (int r = 0; r < 16; r++) inv[r] = 1.0f / lacc[r];
        #pragma unroll
        for (int ht = 0; ht < 2; ht++)
            #pragma unroll
            for (int r = 0; r < 16; r++) {
                int q = q0 + wq * 32 + (r & 3) + 8 * (r >> 2) + 4 * h;
                O[base + (size_t)q * 64 + ht * 32 + l32] = f2bf(o[ht][r] * inv[r]);
            }
    }
}

extern "C" void kernel_launch(void* const* d_in, const int* in_sizes, int n_in,
                              void* d_out, int out_size, void* d_ws, size_t ws_size,
                              hipStream_t stream) {
    const float* x  = (const float*)d_in[0];
    const float* Wq = (const float*)d_in[1];
    const float* bq = (const float*)d_in[2];
    const float* Wk = (const float*)d_in[3];
    const float* bk = (const float*)d_in[4];
    const float* Wv = (const float*)d_in[5];
    const float* bv = (const float*)d_in[6];
    const float* Wo = (const float*)d_in[7];
    const float* bo = (const float*)d_in[8];
    float* out = (float*)d_out;

    // d_out as scratch during prep+proj (dead until final GEMM)
    u16* xbf = (u16*)d_out;
    u16* wqt = xbf + 4194304;
    u16* wkt = wqt + 1048576;
    u16* wvt = wkt + 1048576;

    u16* qws  = (u16*)d_ws;               // Q, later attnout (head layout)
    u16* kws  = qws + 4194304;            // K head layout; later Wo^T
    u16* vtws = kws + 4194304;            // V^T [bh][hd][s]
    u16* wot  = kws;

    prep_x<<<4096, 256, 0, stream>>>(x, xbf);
    prep_wt3<<<dim3(16, 16, 3), 256, 0, stream>>>(Wq, Wk, Wv, wqt, wkt, wvt);

    gemm_qkv_z<<<dim3(8, 32, 3), 256, 0, stream>>>(wqt, wkt, wvt, xbf, bq, bk, bv,
                                                   qws, kws, vtws);

    attn_mfma<<<dim3(16, 32), 512, 0, stream>>>(qws, kws, vtws, qws);

    prep_wt1<<<dim3(16, 16), 256, 0, stream>>>(Wo, wot);
    gemm_out<<<dim3(16, 32), 256, 0, stream>>>(wot, qws, bo, out);
}